// Round 1
// baseline (418.888 us; speedup 1.0000x reference)
//
#include <hip/hip_runtime.h>

// Persistent fused 2-layer LSTM + FC + softmax for MI355X (gfx950).
// B=2048, T=256, H=64, IN=42.
//
// R9: 512 blocks x 256 threads (4 waves), 4 batch rows per block -> 2
// independent blocks per CU (independent barriers: when one block convoys
// at its barrier, the other computes). Each wave computes BOTH layers
// (layer0 step i, layer1 step i-1) -> two independent MFMA/activation
// chains per wave for latency hiding.
//
// LDS: one combined ping-pong row per batch row m:
//   [0..63] h0 | [64..105] x | [106..127] 0-pad | [128..191] h1 | pad
// - layer0 A-frag = k[0..127] = [h0|x|pad]; layer1 A-frag = [h0 | h1],
//   so layer1 reuses layer0's first two K-chunks (6 ds_read_b128, not 8).
// - h0 written once (shared by both consumers).
// - 4 rows stored once; A-tile row c reads batch row c>>2 (broadcast).
// - row stride 208 f16 = 104 words ( ≡ 8 mod 32): fragment-read chunks map
//   2 per bank-group -> conflict-free.
// - MFMA C operand = persistent zero reg; bias added as scalar in the
//   activation (kills the 16 acc-init v_movs per iteration per wave).

typedef _Float16 f16;
typedef _Float16 f16x2 __attribute__((ext_vector_type(2)));
typedef _Float16 f16x8 __attribute__((ext_vector_type(8)));
typedef float f32x4 __attribute__((ext_vector_type(4)));

namespace {
constexpr int kT = 256;
constexpr int kIn = 42;
constexpr int kH = 64;
constexpr int kRows = 4;      // batch rows per block
constexpr int kThr = 256;     // 4 waves
constexpr int kRP = 208;      // combined row stride in f16 (416 B)
constexpr int kSlot = kRows * kRP;
constexpr int kBlocks = 512;  // 2048 / 4 -> 2 blocks per CU
}

__device__ __forceinline__ float sig_(float v) {
  return __fdividef(1.0f, 1.0f + __expf(-v));
}
__device__ __forceinline__ float tnh_(float v) {
  return __fdividef(2.0f, 1.0f + __expf(-2.0f * v)) - 1.0f;
}

__global__ __launch_bounds__(kThr, 2)
void lstm_m_kernel(const float* __restrict__ x,
                   const float* __restrict__ Wih0, const float* __restrict__ Whh0,
                   const float* __restrict__ bih0, const float* __restrict__ bhh0,
                   const float* __restrict__ Wih1, const float* __restrict__ Whh1,
                   const float* __restrict__ bih1, const float* __restrict__ bhh1,
                   const float* __restrict__ Wfc, const float* __restrict__ bfc,
                   float* __restrict__ out) {
  __shared__ __align__(16) f16 xh[2 * kSlot];
  __shared__ float lg[kRows * 8];

  const int tid = threadIdx.x;
  const int w = tid >> 6;       // wave -> gate-col slice [16w, 16w+16)
  const int l = tid & 63;
  const int c = l & 15;
  const int quad = l >> 4;
  const int row0 = blockIdx.x * kRows;

  for (int i = tid; i < 2 * kSlot; i += kThr) xh[i] = (f16)0;

  // ---- one-time: both layers' weights as MFMA B-fragments + biases ----
  f16x8 B0[4][4], B1[4][4];
  float bias0[4], bias1[4];
#pragma unroll
  for (int a = 0; a < 4; ++a) {
    const int g = (w + 4 * a) * 16 + c;
    bias0[a] = bih0[g] + bhh0[g];
    bias1[a] = bih1[g] + bhh1[g];
#pragma unroll
    for (int q = 0; q < 4; ++q) {
      f16x8 v0, v1;
#pragma unroll
      for (int j = 0; j < 8; ++j) {
        const int k = q * 32 + quad * 8 + j;
        // layer0 A = [h0 | x | 0]:  k<64 -> Whh0, 64<=k<106 -> Wih0, else 0
        const float w0 = (k < 64) ? Whh0[g * kH + k]
                       : (k < 106) ? Wih0[g * kIn + (k - 64)] : 0.f;
        // layer1 A = [h0 | h1]:     k<64 -> Wih1 (input is h0), else Whh1
        const float w1 = (k < 64) ? Wih1[g * kH + k] : Whh1[g * kH + (k - 64)];
        v0[j] = (f16)w0;
        v1[j] = (f16)w1;
      }
      B0[a][q] = v0;
      B1[a][q] = v1;
    }
  }

  // Lane's A-tile source row (4 real rows, 4x lane broadcast) and its
  // activated output cell: batch row = quad, col = hcol, acc reg 0.
  const int arow = c >> 2;
  const int hcol = w * 16 + c;
  float c0 = 0.f, c1 = 0.f;
  const f32x4 zero4 = {0.f, 0.f, 0.f, 0.f};

  // x staging: wave w stages batch row w; 21 lanes x float2 = 42 floats.
  const float* xrow = x + (size_t)(row0 + w) * kT * kIn;
  if (l < 21) {  // pre-stage x(0) into slot 0
    const float2 v = *(const float2*)(xrow + 2 * l);
    f16x2 hv; hv.x = (f16)v.x; hv.y = (f16)v.y;
    *(f16x2*)&xh[w * kRP + 64 + 2 * l] = hv;
  }
  __syncthreads();

  // iter i: layer0 computes h0(i) (i<kT), layer1 computes h1(i-1) (i>0).
  for (int i = 0; i <= kT; ++i) {
    const int cur = i & 1, nxt = cur ^ 1;
    const bool act0 = (i < kT), act1 = (i > 0);

    float2 xv;
    const bool havex = (l < 21) && (i + 1 < kT);
    if (havex) xv = *(const float2*)(xrow + (size_t)(i + 1) * kIn + 2 * l);

    const f16* base = xh + cur * kSlot + arow * kRP + quad * 8;
    f16x8 A0[4], A1h[2];
#pragma unroll
    for (int q = 0; q < 4; ++q)
      A0[q] = __builtin_bit_cast(f16x8, *(const float4*)(base + q * 32));
#pragma unroll
    for (int q = 0; q < 2; ++q)
      A1h[q] = __builtin_bit_cast(f16x8, *(const float4*)(base + 128 + q * 32));

    // 32 MFMA in one straight-line block: 8 independent 4-deep chains.
    // Unconditional at the edges: i==kT reads stale x (finite, result
    // discarded); i==0 layer1 reads zeros (state guarded by select below).
    f32x4 ac0[4], ac1[4];
#pragma unroll
    for (int a = 0; a < 4; ++a) {
      ac0[a] = __builtin_amdgcn_mfma_f32_16x16x32_f16(A0[0], B0[a][0], zero4, 0, 0, 0);
      ac1[a] = __builtin_amdgcn_mfma_f32_16x16x32_f16(A0[0], B1[a][0], zero4, 0, 0, 0);
    }
#pragma unroll
    for (int a = 0; a < 4; ++a) {
      ac0[a] = __builtin_amdgcn_mfma_f32_16x16x32_f16(A0[1], B0[a][1], ac0[a], 0, 0, 0);
      ac1[a] = __builtin_amdgcn_mfma_f32_16x16x32_f16(A0[1], B1[a][1], ac1[a], 0, 0, 0);
    }
#pragma unroll
    for (int a = 0; a < 4; ++a) {
      ac0[a] = __builtin_amdgcn_mfma_f32_16x16x32_f16(A0[2], B0[a][2], ac0[a], 0, 0, 0);
      ac1[a] = __builtin_amdgcn_mfma_f32_16x16x32_f16(A1h[0], B1[a][2], ac1[a], 0, 0, 0);
    }
#pragma unroll
    for (int a = 0; a < 4; ++a) {
      ac0[a] = __builtin_amdgcn_mfma_f32_16x16x32_f16(A0[3], B0[a][3], ac0[a], 0, 0, 0);
      ac1[a] = __builtin_amdgcn_mfma_f32_16x16x32_f16(A1h[1], B1[a][3], ac1[a], 0, 0, 0);
    }

    // layer0 cell (c0 garbage at i==kT is dead; write gated)
    {
      const float gi = ac0[0][0] + bias0[0], gf = ac0[1][0] + bias0[1];
      const float gg = ac0[2][0] + bias0[2], go = ac0[3][0] + bias0[3];
      c0 = sig_(gf) * c0 + sig_(gi) * tnh_(gg);
      const float h0v = sig_(go) * tnh_(c0);
      if (act0) xh[nxt * kSlot + quad * kRP + hcol] = (f16)h0v;
    }
    // layer1 cell (state + write guarded branch-free at i==0)
    {
      const float gi = ac1[0][0] + bias1[0], gf = ac1[1][0] + bias1[1];
      const float gg = ac1[2][0] + bias1[2], go = ac1[3][0] + bias1[3];
      const float c1n = sig_(gf) * c1 + sig_(gi) * tnh_(gg);
      c1 = act1 ? c1n : c1;
      const float h1v = sig_(go) * tnh_(c1n);
      xh[nxt * kSlot + quad * kRP + 128 + hcol] = act1 ? (f16)h1v : (f16)0;
    }
    if (havex) {
      f16x2 hv; hv.x = (f16)xv.x; hv.y = (f16)xv.y;
      *(f16x2*)&xh[nxt * kSlot + w * kRP + 64 + 2 * l] = hv;
    }
    __syncthreads();  // publish nxt; next iter reads it as cur
  }

  // ---- FC + softmax. Final h1(T-1) landed in slot (kT&1)^1 = 1. ----
  if (tid < kRows * 5) {
    const int rr = tid / 5, oo = tid - rr * 5;
    float a = bfc[oo];
#pragma unroll
    for (int j = 0; j < kH; ++j)
      a += (float)xh[kSlot + rr * kRP + 128 + j] * Wfc[oo * kH + j];
    lg[rr * 8 + oo] = a;
  }
  __syncthreads();
  if (tid < kRows) {
    const float v0 = lg[tid * 8 + 0], v1 = lg[tid * 8 + 1], v2 = lg[tid * 8 + 2],
                v3 = lg[tid * 8 + 3], v4 = lg[tid * 8 + 4];
    const float m = fmaxf(fmaxf(fmaxf(v0, v1), fmaxf(v2, v3)), v4);
    const float e0 = __expf(v0 - m), e1 = __expf(v1 - m), e2 = __expf(v2 - m),
                e3 = __expf(v3 - m), e4 = __expf(v4 - m);
    const float inv = __fdividef(1.0f, e0 + e1 + e2 + e3 + e4);
    float* o = out + (size_t)(row0 + tid) * 5;
    o[0] = e0 * inv; o[1] = e1 * inv; o[2] = e2 * inv; o[3] = e3 * inv; o[4] = e4 * inv;
  }
}

extern "C" void kernel_launch(void* const* d_in, const int* in_sizes, int n_in,
                              void* d_out, int out_size, void* d_ws, size_t ws_size,
                              hipStream_t stream) {
  (void)in_sizes; (void)n_in; (void)d_ws; (void)ws_size; (void)out_size;
  lstm_m_kernel<<<dim3(kBlocks), dim3(kThr), 0, stream>>>(
      (const float*)d_in[0],
      (const float*)d_in[1], (const float*)d_in[2],
      (const float*)d_in[3], (const float*)d_in[4],
      (const float*)d_in[5], (const float*)d_in[6],
      (const float*)d_in[7], (const float*)d_in[8],
      (const float*)d_in[9], (const float*)d_in[10],
      (float*)d_out);
}

// Round 4
// 384.697 us; speedup vs baseline: 1.0889x; 1.0889x over previous
//
#include <hip/hip_runtime.h>

// Persistent fused 2-layer LSTM + FC + softmax for MI355X (gfx950).
// B=2048, T=256, H=64, IN=42. 256 blocks x 512 threads; block owns 8 rows.
// Waves 0-3 (A): layer0(step i); waves 4-7 (B): layer1(step i-1).
//
// R12 = R11 with the slot-size bug fixed: MFMA A-tiles span 16 LDS rows
// (lane reads row c = l&15; interleaved m-map puts the 8 real batch rows
// at {0,1,4,5,8,9,12,13}, rest stay zero). R10/R11 sized slots for 8 rows
// -> OOB reads/writes -> NaN. Slots are 16 rows again (R8-style).
//
// Instruction diet vs R8 (303us):
//  1) bias rides as the MFMA C-operand (f32x4 splat) -> no acc-init movs.
//  2) weights/biases pre-scaled by log2e (sigma gates) / 2*log2e (g gate)
//     at f16-conversion time -> activations are pure exp2 with free VOP3
//     neg modifier. Algebraically identical.
//  3) unified LDS layout: xh0 row = [h0 64 | x 42 | pad], xh1 = [h1 64|pad].
//     Layer1 A-chunks 0-1 read h0 directly from xh0 -> h0 written ONCE.
//  4) 2x unrolled ping-pong loop, LDS pointers hoisted per parity,
//     running global x pointer -> no per-iter cur/nxt address arithmetic.

typedef _Float16 f16;
typedef _Float16 f16x2 __attribute__((ext_vector_type(2)));
typedef _Float16 f16x8 __attribute__((ext_vector_type(8)));
typedef float f32x4 __attribute__((ext_vector_type(4)));

namespace {
constexpr int kT = 256;
constexpr int kIn = 42;
constexpr int kH = 64;
constexpr int kRows = 8;          // real batch rows per block
constexpr int kTileR = 16;        // LDS rows per slot (MFMA A-tile height)
constexpr int kThr = 512;
constexpr int kP0 = 136;          // xh0 row stride (f16): [h0 64 | x 42 | pad]
constexpr int kS0 = kTileR * kP0; // one ping-pong slot of xh0
constexpr int kP1 = 72;           // xh1 row stride (f16): [h1 64 | pad]
constexpr int kS1 = kTileR * kP1;
constexpr float kL2E = 1.44269504088896f;  // log2(e)
}

__device__ __forceinline__ float ex2_(float v) {
  return __builtin_amdgcn_exp2f(v);
}

__global__ __launch_bounds__(kThr, 2)
void lstm_r12_kernel(const float* __restrict__ x,
                     const float* __restrict__ Wih0, const float* __restrict__ Whh0,
                     const float* __restrict__ bih0, const float* __restrict__ bhh0,
                     const float* __restrict__ Wih1, const float* __restrict__ Whh1,
                     const float* __restrict__ bih1, const float* __restrict__ bhh1,
                     const float* __restrict__ Wfc, const float* __restrict__ bfc,
                     float* __restrict__ out) {
  __shared__ __align__(16) f16 xh0[2 * kS0];
  __shared__ __align__(16) f16 xh1[2 * kS1];
  __shared__ float lg[kRows * 8];

  const int tid = threadIdx.x;
  const int w8 = tid >> 6;
  const bool isA = (w8 < 4);     // A: layer 0; B: layer 1
  const int w = w8 & 3;          // gate-col slice [16w, 16w+16)
  const int l = tid & 63;
  const int c = l & 15;
  const int quad = l >> 4;
  const int row0 = blockIdx.x * kRows;

  for (int i = tid; i < 2 * kS0; i += kThr) xh0[i] = (f16)0;
  for (int i = tid; i < 2 * kS1; i += kThr) xh1[i] = (f16)0;

  // ---- one-time: weights as MFMA B-fragments (pre-scaled) + bias4 ----
  f16x8 Bw[4][4];
  f32x4 bias4[4];
#pragma unroll
  for (int a = 0; a < 4; ++a) {
    const int g = (w + 4 * a) * 16 + c;
    const float scale = (a == 2) ? 2.0f * kL2E : kL2E;  // g-gate gets 2*log2e
    const float b = (isA ? (bih0[g] + bhh0[g]) : (bih1[g] + bhh1[g])) * scale;
    bias4[a] = (f32x4){b, b, b, b};
#pragma unroll
    for (int q = 0; q < 4; ++q) {
      f16x8 v;
#pragma unroll
      for (int j = 0; j < 8; ++j) {
        const int k = q * 32 + quad * 8 + j;
        float wv;
        if (isA)  // layer0 A = [h0 | x | 0]
          wv = (k < 64) ? Whh0[g * kH + k] : (k < 106) ? Wih0[g * kIn + (k - 64)] : 0.f;
        else      // layer1 A = [h0 | h1]
          wv = (k < 64) ? Wih1[g * kH + k] : Whh1[g * kH + (k - 64)];
        v[j] = (f16)(wv * scale);
      }
      Bw[a][q] = v;
    }
  }

  // ---- hoisted per-parity LDS pointers ----
  // A-frag reads: lane reads LDS row c. Chunks 0,1 (k 0..63) from xh0;
  // chunks 2,3 from xh0+64 (A: x|pad) or xh1 (B: h1).
  const f16* rb0[2];
  const f16* rb23[2];
  rb0[0] = xh0 + c * kP0 + quad * 8;
  rb0[1] = rb0[0] + kS0;
  rb23[0] = isA ? (rb0[0] + 64) : (xh1 + c * kP1 + quad * 8);
  rb23[1] = rb23[0] + (isA ? kS0 : kS1);

  // h writes: cell i2 -> LDS row quad*4+i2 (interleaved m-map), col hcol.
  const int hcol = w * 16 + c;
  const int wst = isA ? kP0 : kP1;
  f16* wp[2];
  {
    f16* base = isA ? xh0 : xh1;
    wp[0] = base + (quad * 4) * wst + hcol;
    wp[1] = wp[0] + (isA ? kS0 : kS1);
  }

  float cst[2] = {0.f, 0.f};

  // x staging: 168 group-B threads, one float2 each; batch row srr -> LDS
  // row sm = (srr>>1)*4 + (srr&1). Writes into xh0 col 64+2sp.
  const int stid = tid - 256;
  const bool stager = (!isA) && (stid < 168);
  const int srr = stager ? stid / 21 : 0;
  const int sp = stager ? stid - srr * 21 : 0;
  const int sm = ((srr >> 1) << 2) | (srr & 1);
  const float* xrow = x + (size_t)(row0 + srr) * kT * kIn;
  f16* xwp[2];
  xwp[0] = xh0 + sm * kP0 + 64 + 2 * sp;
  xwp[1] = xwp[0] + kS0;

  if (stager) {  // pre-stage x(0) into slot 0
    const float2 v = *(const float2*)(xrow + 2 * sp);
    f16x2 hv; hv.x = (f16)v.x; hv.y = (f16)v.y;
    *(f16x2*)xwp[0] = hv;
  }
  const float* xp = xrow + kIn + 2 * sp;  // x(i+1) for body i=0
  __syncthreads();

  auto step = [&](int i, int par) {
    const int nxt = par ^ 1;
    const bool act = isA ? (i < kT) : (i > 0);

    float2 xv;
    const bool havex = stager && (i + 1 < kT);
    if (havex) xv = *(const float2*)xp;

    if (act) {
      const f16x8 A0 = __builtin_bit_cast(f16x8, *(const float4*)(rb0[par]));
      const f16x8 A1 = __builtin_bit_cast(f16x8, *(const float4*)(rb0[par] + 32));
      const f16x8 A2 = __builtin_bit_cast(f16x8, *(const float4*)(rb23[par]));
      const f16x8 A3 = __builtin_bit_cast(f16x8, *(const float4*)(rb23[par] + 32));
      f32x4 acc[4];
#pragma unroll
      for (int a = 0; a < 4; ++a)
        acc[a] = __builtin_amdgcn_mfma_f32_16x16x32_f16(A0, Bw[a][0], bias4[a], 0, 0, 0);
#pragma unroll
      for (int a = 0; a < 4; ++a)
        acc[a] = __builtin_amdgcn_mfma_f32_16x16x32_f16(A1, Bw[a][1], acc[a], 0, 0, 0);
#pragma unroll
      for (int a = 0; a < 4; ++a)
        acc[a] = __builtin_amdgcn_mfma_f32_16x16x32_f16(A2, Bw[a][2], acc[a], 0, 0, 0);
#pragma unroll
      for (int a = 0; a < 4; ++a)
        acc[a] = __builtin_amdgcn_mfma_f32_16x16x32_f16(A3, Bw[a][3], acc[a], 0, 0, 0);

      // gates arrive pre-scaled: sigma(v) = rcp(1+exp2(-v')),
      // tanh(g) = 2*rcp(1+exp2(-g'')) - 1  (g'' carries the 2*log2e).
#pragma unroll
      for (int i2 = 0; i2 < 2; ++i2) {
        const float ei = ex2_(-acc[0][i2]);
        const float ef = ex2_(-acc[1][i2]);
        const float eg = ex2_(-acc[2][i2]);
        const float eo = ex2_(-acc[3][i2]);
        const float si = __fdividef(1.0f, 1.0f + ei);
        const float sf = __fdividef(1.0f, 1.0f + ef);
        const float tg = __fdividef(2.0f, 1.0f + eg) - 1.0f;
        const float so = __fdividef(1.0f, 1.0f + eo);
        cst[i2] = sf * cst[i2] + si * tg;
        const float ec = ex2_(cst[i2] * (-2.0f * kL2E));
        const float tc = __fdividef(2.0f, 1.0f + ec) - 1.0f;
        wp[nxt][i2 * wst] = (f16)(so * tc);
      }
    }
    if (havex) {
      f16x2 hv; hv.x = (f16)xv.x; hv.y = (f16)xv.y;
      *(f16x2*)xwp[nxt] = hv;
    }
    xp += kIn;
    __syncthreads();  // publish nxt-slot writes; next step reads them as cur
  };

  for (int i = 0; i < kT; i += 2) { step(i, 0); step(i + 1, 1); }
  step(kT, 0);  // drain: B computes h1(T-1) -> xh1 slot 1

  // ---- FC + softmax. Final h1(T-1) is in xh1 slot 1. ----
  if (tid < kRows * 5) {
    const int rr = tid / 5, oo = tid - rr * 5;
    const int m = ((rr >> 1) << 2) | (rr & 1);
    float a = bfc[oo];
#pragma unroll
    for (int j = 0; j < kH; ++j)
      a += (float)xh1[kS1 + m * kP1 + j] * Wfc[oo * kH + j];
    lg[rr * 8 + oo] = a;
  }
  __syncthreads();
  if (tid < kRows) {
    const float v0 = lg[tid * 8 + 0], v1 = lg[tid * 8 + 1], v2 = lg[tid * 8 + 2],
                v3 = lg[tid * 8 + 3], v4 = lg[tid * 8 + 4];
    const float m = fmaxf(fmaxf(fmaxf(v0, v1), fmaxf(v2, v3)), v4);
    const float e0 = __expf(v0 - m), e1 = __expf(v1 - m), e2 = __expf(v2 - m),
                e3 = __expf(v3 - m), e4 = __expf(v4 - m);
    const float inv = __fdividef(1.0f, e0 + e1 + e2 + e3 + e4);
    float* o = out + (size_t)(row0 + tid) * 5;
    o[0] = e0 * inv; o[1] = e1 * inv; o[2] = e2 * inv; o[3] = e3 * inv; o[4] = e4 * inv;
  }
}

extern "C" void kernel_launch(void* const* d_in, const int* in_sizes, int n_in,
                              void* d_out, int out_size, void* d_ws, size_t ws_size,
                              hipStream_t stream) {
  (void)in_sizes; (void)n_in; (void)d_ws; (void)ws_size; (void)out_size;
  lstm_r12_kernel<<<dim3(256), dim3(kThr), 0, stream>>>(
      (const float*)d_in[0],
      (const float*)d_in[1], (const float*)d_in[2],
      (const float*)d_in[3], (const float*)d_in[4],
      (const float*)d_in[5], (const float*)d_in[6],
      (const float*)d_in[7], (const float*)d_in[8],
      (const float*)d_in[9], (const float*)d_in[10],
      (float*)d_out);
}

// Round 6
// 270.475 us; speedup vs baseline: 1.5487x; 1.4223x over previous
//
#include <hip/hip_runtime.h>

// Persistent fused 2-layer LSTM + FC + softmax for MI355X (gfx950).
// B=2048, T=256, H=64, IN=42. 256 blocks x 512 threads; block owns 8 rows.
// Waves 0-3 (A): layer0(step i); waves 4-7 (B): layer1(step i-1).
//
// R14 = R13 with cvt_pkrtz results bit_cast to _Float16x2 (the builtin
// returns __fp16x2; clang rejects the implicit conversion). Changes vs
// R12 (293us):
//  1) x feeds layer0's MFMA chunks 2,3 DIRECTLY from per-lane global loads
//     (prefetched 2 steps ahead into registers). Safe because MFMA D-rows
//     are row-independent: pad tile-rows' garbage lands in discarded D
//     rows, and k>=106 weight columns are zero (masks x-row tail overrun;
//     a single global-end clamp prevents OOB faults). Removes the stager
//     path, all x LDS writes, and 2 of 4 A-wave LDS fragment reads; A's
//     MFMA now starts on register x-chunks while h0 ds_reads are in flight.
//  2) common-denominator activations: 10 trans/cell -> 7 (5 exp2 + 2 rcp):
//     c' = [c(1+ei)(1+eg) + (1-eg)(1+ef)] / [(1+ef)(1+ei)(1+eg)]
//     h  = (1-ec) / [(1+ec)(1+eo)],  ec = exp2(-2*log2e*c')
//     with direct v_rcp_f32. Algebraically identical to sigmoid/tanh form.
//  3) LDS shrinks: xh0/xh1 rows are [h 64 | pad 8] (stride 72 f16, 144B).

typedef _Float16 f16;
typedef _Float16 f16x2 __attribute__((ext_vector_type(2)));
typedef _Float16 f16x8 __attribute__((ext_vector_type(8)));
typedef __fp16 hf16x2 __attribute__((ext_vector_type(2)));
typedef float f32x4 __attribute__((ext_vector_type(4)));

namespace {
constexpr int kT = 256;
constexpr int kIn = 42;
constexpr int kH = 64;
constexpr int kRows = 8;          // real batch rows per block
constexpr int kThr = 512;
constexpr int kP = 72;            // LDS row stride in f16 (144 B): [h 64 | pad]
constexpr int kS = 16 * kP;       // one ping-pong slot (16 tile rows)
constexpr float kL2E = 1.44269504088896f;   // log2(e)
constexpr float kM2L = -2.0f * kL2E;
constexpr unsigned kNTot = 2048u * 256u * 42u;   // total floats in x
constexpr unsigned kOfsMax = kNTot - 64u;        // clamp so +63 floats stays in-bounds
}

__device__ __forceinline__ float ex2_(float v) { return __builtin_amdgcn_exp2f(v); }
__device__ __forceinline__ float rcp_(float v) { return __builtin_amdgcn_rcpf(v); }
__device__ __forceinline__ f16x2 pk_(float a, float b) {
  return __builtin_bit_cast(f16x2, __builtin_amdgcn_cvt_pkrtz(a, b));
}

__global__ __launch_bounds__(kThr, 2)
void lstm_r14_kernel(const float* __restrict__ x,
                     const float* __restrict__ Wih0, const float* __restrict__ Whh0,
                     const float* __restrict__ bih0, const float* __restrict__ bhh0,
                     const float* __restrict__ Wih1, const float* __restrict__ Whh1,
                     const float* __restrict__ bih1, const float* __restrict__ bhh1,
                     const float* __restrict__ Wfc, const float* __restrict__ bfc,
                     float* __restrict__ out) {
  __shared__ __align__(16) f16 xh0[2 * kS];
  __shared__ __align__(16) f16 xh1[2 * kS];
  __shared__ float lg[kRows * 8];

  const int tid = threadIdx.x;
  const int w8 = tid >> 6;
  const bool isA = (w8 < 4);     // A: layer 0; B: layer 1
  const int w = w8 & 3;          // gate-col slice [16w, 16w+16)
  const int l = tid & 63;
  const int c = l & 15;
  const int quad = l >> 4;
  const int row0 = blockIdx.x * kRows;

  for (int i = tid; i < 2 * kS; i += kThr) { xh0[i] = (f16)0; xh1[i] = (f16)0; }

  // ---- one-time: weights as MFMA B-fragments (pre-scaled) + bias4 ----
  f16x8 Bw[4][4];
  f32x4 bias4[4];
#pragma unroll
  for (int a = 0; a < 4; ++a) {
    const int g = (w + 4 * a) * 16 + c;
    const float scale = (a == 2) ? 2.0f * kL2E : kL2E;  // g-gate gets 2*log2e
    const float b = (isA ? (bih0[g] + bhh0[g]) : (bih1[g] + bhh1[g])) * scale;
    bias4[a] = (f32x4){b, b, b, b};
#pragma unroll
    for (int q = 0; q < 4; ++q) {
      f16x8 v;
#pragma unroll
      for (int j = 0; j < 8; ++j) {
        const int k = q * 32 + quad * 8 + j;
        float wv;
        if (isA)  // layer0 A = [h0 (k<64) | x (64<=k<106) | 0]
          wv = (k < 64) ? Whh0[g * kH + k] : (k < 106) ? Wih0[g * kIn + (k - 64)] : 0.f;
        else      // layer1 A = [h0 (k<64) | h1]
          wv = (k < 64) ? Wih1[g * kH + k] : Whh1[g * kH + (k - 64)];
        v[j] = (f16)(wv * scale);
      }
      Bw[a][q] = v;
    }
  }

  // ---- LDS pointers (lane reads tile row c) ----
  const f16* rbh[2];   // h0 chunks 0,1 (A and B)
  rbh[0] = xh0 + c * kP + quad * 8;
  rbh[1] = rbh[0] + kS;
  const f16* rb1[2];   // h1 chunks (B only)
  rb1[0] = xh1 + c * kP + quad * 8;
  rb1[1] = rb1[0] + kS;

  // h writes: cell i2 -> tile row quad*4+i2 (interleaved m-map), col hcol.
  const int hcol = w * 16 + c;
  f16* wp[2];
  {
    f16* base = isA ? xh0 : xh1;
    wp[0] = base + (quad * 4) * kP + hcol;
    wp[1] = wp[0] + kS;
  }

  float cst[2] = {0.f, 0.f};

  // ---- A-wave register x pipeline (prefetch depth 2) ----
  // Lane's x batch row: pad lanes (c&2) alias a real row; their MFMA
  // products land in discarded D rows. fc3 tail (>=42) is masked by the
  // zero weight columns; kOfsMax clamp keeps loads in-bounds.
  const int xr = ((c >> 2) << 1) | (c & 1);
  const unsigned fc2 = (unsigned)(quad * 8);
  const unsigned fc3 = 32u + (unsigned)(quad * 8);
  unsigned ofs = (unsigned)(row0 + xr) * (unsigned)(kT * kIn);

  float2 rawA[8], rawB[8];
  f16x8 fx2{}, fx3{};

  auto issueX = [&](float2 (&r)[8], unsigned o) {
    const float* p = x + (o < kOfsMax ? o : kOfsMax);
#pragma unroll
    for (int j = 0; j < 4; ++j) {
      r[j]     = *(const float2*)(p + fc2 + 2 * j);
      r[4 + j] = *(const float2*)(p + fc3 + 2 * j);
    }
  };
  auto cvtX = [&](const float2 (&r)[8]) {
    struct H4 { f16x2 a, b, c, d; };
    H4 h2, h3;
    h2.a = pk_(r[0].x, r[0].y);
    h2.b = pk_(r[1].x, r[1].y);
    h2.c = pk_(r[2].x, r[2].y);
    h2.d = pk_(r[3].x, r[3].y);
    h3.a = pk_(r[4].x, r[4].y);
    h3.b = pk_(r[5].x, r[5].y);
    h3.c = pk_(r[6].x, r[6].y);
    h3.d = pk_(r[7].x, r[7].y);
    fx2 = __builtin_bit_cast(f16x8, h2);
    fx3 = __builtin_bit_cast(f16x8, h3);
  };

  if (isA) {
    issueX(rawB, ofs);            // x(0)
    cvtX(rawB);                   // fragX = x(0)
    issueX(rawA, ofs + kIn);      // x(1) in flight
    ofs += 2u * kIn;              // next issue: t = 2
  }
  __syncthreads();

  // iter i: A computes layer0(t=i) (i<kT), B computes layer1(t=i-1) (i>0).
  auto step = [&](int i, int par, bool even) {
    const int nxt = par ^ 1;
    const bool act = isA ? (i < kT) : (i > 0);

    if (act) {
      f32x4 acc[4];
      if (isA) {
        // x chunks first: register-resident, overlap the h0 ds_reads.
#pragma unroll
        for (int a = 0; a < 4; ++a)
          acc[a] = __builtin_amdgcn_mfma_f32_16x16x32_f16(fx2, Bw[a][2], bias4[a], 0, 0, 0);
#pragma unroll
        for (int a = 0; a < 4; ++a)
          acc[a] = __builtin_amdgcn_mfma_f32_16x16x32_f16(fx3, Bw[a][3], acc[a], 0, 0, 0);
        const f16x8 A0 = __builtin_bit_cast(f16x8, *(const float4*)(rbh[par]));
        const f16x8 A1 = __builtin_bit_cast(f16x8, *(const float4*)(rbh[par] + 32));
#pragma unroll
        for (int a = 0; a < 4; ++a)
          acc[a] = __builtin_amdgcn_mfma_f32_16x16x32_f16(A0, Bw[a][0], acc[a], 0, 0, 0);
#pragma unroll
        for (int a = 0; a < 4; ++a)
          acc[a] = __builtin_amdgcn_mfma_f32_16x16x32_f16(A1, Bw[a][1], acc[a], 0, 0, 0);
      } else {
        const f16x8 A0 = __builtin_bit_cast(f16x8, *(const float4*)(rbh[par]));
        const f16x8 A1 = __builtin_bit_cast(f16x8, *(const float4*)(rbh[par] + 32));
        const f16x8 A2 = __builtin_bit_cast(f16x8, *(const float4*)(rb1[par]));
        const f16x8 A3 = __builtin_bit_cast(f16x8, *(const float4*)(rb1[par] + 32));
#pragma unroll
        for (int a = 0; a < 4; ++a)
          acc[a] = __builtin_amdgcn_mfma_f32_16x16x32_f16(A0, Bw[a][0], bias4[a], 0, 0, 0);
#pragma unroll
        for (int a = 0; a < 4; ++a)
          acc[a] = __builtin_amdgcn_mfma_f32_16x16x32_f16(A1, Bw[a][1], acc[a], 0, 0, 0);
#pragma unroll
        for (int a = 0; a < 4; ++a)
          acc[a] = __builtin_amdgcn_mfma_f32_16x16x32_f16(A2, Bw[a][2], acc[a], 0, 0, 0);
#pragma unroll
        for (int a = 0; a < 4; ++a)
          acc[a] = __builtin_amdgcn_mfma_f32_16x16x32_f16(A3, Bw[a][3], acc[a], 0, 0, 0);
      }

      // common-denominator activation (7 trans/cell: 5 exp2 + 2 rcp)
#pragma unroll
      for (int i2 = 0; i2 < 2; ++i2) {
        const float ei = ex2_(-acc[0][i2]);
        const float ef = ex2_(-acc[1][i2]);
        const float eg = ex2_(-acc[2][i2]);
        const float eo = ex2_(-acc[3][i2]);
        const float pi = 1.0f + ei, pf = 1.0f + ef, pg = 1.0f + eg, po = 1.0f + eo;
        const float mg = 1.0f - eg;
        const float t1 = pi * pg;
        const float t2 = mg * pf;
        const float N  = fmaf(cst[i2], t1, t2);
        const float cn = N * rcp_(t1 * pf);
        cst[i2] = cn;
        const float ec = ex2_(cn * kM2L);
        const float h  = (1.0f - ec) * rcp_(po * (1.0f + ec));
        wp[nxt][i2 * kP] = (f16)h;
      }
    }
    if (isA) {
      if (even) { issueX(rawB, ofs); cvtX(rawA); }   // issue x(i+2), cvt x(i+1)
      else      { issueX(rawA, ofs); cvtX(rawB); }
      ofs += (unsigned)kIn;
    }
    __syncthreads();  // publish nxt-slot writes; next step reads them as cur
  };

  for (int i = 0; i < kT; i += 2) { step(i, 0, true); step(i + 1, 1, false); }
  step(kT, 0, true);  // drain: B computes h1(T-1) -> xh1 slot 1

  // ---- FC + softmax. Final h1(T-1) is in xh1 slot 1. ----
  if (tid < kRows * 5) {
    const int rr = tid / 5, oo = tid - rr * 5;
    const int m = ((rr >> 1) << 2) | (rr & 1);
    float a = bfc[oo];
#pragma unroll
    for (int j = 0; j < kH; ++j)
      a += (float)xh1[kS + m * kP + j] * Wfc[oo * kH + j];
    lg[rr * 8 + oo] = a;
  }
  __syncthreads();
  if (tid < kRows) {
    const float v0 = lg[tid * 8 + 0], v1 = lg[tid * 8 + 1], v2 = lg[tid * 8 + 2],
                v3 = lg[tid * 8 + 3], v4 = lg[tid * 8 + 4];
    const float m = fmaxf(fmaxf(fmaxf(v0, v1), fmaxf(v2, v3)), v4);
    const float e0 = __expf(v0 - m), e1 = __expf(v1 - m), e2 = __expf(v2 - m),
                e3 = __expf(v3 - m), e4 = __expf(v4 - m);
    const float inv = __fdividef(1.0f, e0 + e1 + e2 + e3 + e4);
    float* o = out + (size_t)(row0 + tid) * 5;
    o[0] = e0 * inv; o[1] = e1 * inv; o[2] = e2 * inv; o[3] = e3 * inv; o[4] = e4 * inv;
  }
}

extern "C" void kernel_launch(void* const* d_in, const int* in_sizes, int n_in,
                              void* d_out, int out_size, void* d_ws, size_t ws_size,
                              hipStream_t stream) {
  (void)in_sizes; (void)n_in; (void)d_ws; (void)ws_size; (void)out_size;
  lstm_r14_kernel<<<dim3(256), dim3(kThr), 0, stream>>>(
      (const float*)d_in[0],
      (const float*)d_in[1], (const float*)d_in[2],
      (const float*)d_in[3], (const float*)d_in[4],
      (const float*)d_in[5], (const float*)d_in[6],
      (const float*)d_in[7], (const float*)d_in[8],
      (const float*)d_in[9], (const float*)d_in[10],
      (float*)d_out);
}